// Round 4
// baseline (660.232 us; speedup 1.0000x reference)
//
#include <hip/hip_runtime.h>
#include <hip/hip_bf16.h>
#include <cstdint>
#include <cstddef>

// Problem constants
#define HIDDEN   768
#define HID_F    3072
#define PART     192
#define SHARED_F 576
#define NEXP     6
#define BATCH    32
#define SEQ      1024
#define M_TOK    (BATCH * SEQ)   // 32768

typedef __bf16 bf16;
typedef __attribute__((ext_vector_type(8))) __bf16 bf16x8;
typedef __attribute__((ext_vector_type(4))) __bf16 bf16x4;
typedef __attribute__((ext_vector_type(4))) float  f32x4;

// ---- async global -> LDS copy, 16B per lane -----------------------------
__device__ __forceinline__ void gl2lds16(const void* g, void* l) {
    __builtin_amdgcn_global_load_lds(
        (const __attribute__((address_space(1))) void*)g,
        (__attribute__((address_space(3))) void*)l,
        16, 0, 0);
}

// Exact-GELU via Abramowitz-Stegun 7.1.26 rational erf (|eps| <= 1.5e-7).
__device__ __forceinline__ float gelu_fast(float x) {
    float xs = x * 0.70710678118654752f;       // x / sqrt(2)
    float ax = __builtin_fabsf(xs);
    float t  = __builtin_amdgcn_rcpf(1.0f + 0.3275911f * ax);
    float p  = t * (0.254829592f +
               t * (-0.284496736f +
               t * (1.421413741f +
               t * (-1.453152027f +
               t * 1.061405429f))));
    float e  = __expf(-xs * xs);
    float er = 1.0f - p * e;                   // erf(|xs|)
    er = (xs < 0.0f) ? -er : er;
    return 0.5f * x * (1.0f + er);
}

// ---- prep: fp32 -> bf16 vectorized convert ------------------------------
__global__ __launch_bounds__(256) void cvt_f32_bf16(
        const float4* __restrict__ src, bf16x4* __restrict__ dst, int n4) {
    int i      = blockIdx.x * 256 + threadIdx.x;
    int stride = gridDim.x * 256;
    for (; i < n4; i += stride) {
        float4 v = src[i];
        bf16x4 o = { (__bf16)v.x, (__bf16)v.y, (__bf16)v.z, (__bf16)v.w };
        dst[i] = o;
    }
}

// ---- prep: tiled transpose fp32[K][N] -> bf16[N][K] ---------------------
__global__ __launch_bounds__(256) void transpose_cvt(
        const float* __restrict__ src, bf16* __restrict__ dst, int K, int N) {
    __shared__ float t[32][33];
    const int n0 = blockIdx.x * 32, k0 = blockIdx.y * 32;
    const int tx = threadIdx.x & 31, ty = threadIdx.x >> 5;  // ty in 0..7
#pragma unroll
    for (int p = 0; p < 4; ++p) {
        int r = ty + p * 8;
        t[r][tx] = src[(size_t)(k0 + r) * N + n0 + tx];
    }
    __syncthreads();
#pragma unroll
    for (int p = 0; p < 4; ++p) {
        int rn = ty + p * 8;
        dst[(size_t)(n0 + rn) * K + k0 + tx] = (bf16)t[tx][rn];
    }
}

// ---- prep: Wcat[e][n][k] = (n<576 ? W2[k][n] : We[e][k][n-576]) as bf16 --
__global__ __launch_bounds__(256) void build_wcat(
        const float* __restrict__ W2, const float* __restrict__ We,
        bf16* __restrict__ Wcat) {
    __shared__ float t[32][33];
    const int e  = blockIdx.z;
    const int n0 = blockIdx.x * 32;   // output row tile (col of original)
    const int k0 = blockIdx.y * 32;   // k tile
    const int tx = threadIdx.x & 31, ty = threadIdx.x >> 5;
    const float* src;
    int ld, c;
    if (n0 < SHARED_F) { src = W2; ld = SHARED_F; c = n0 + tx; }
    else { src = We + (size_t)e * HID_F * PART; ld = PART; c = n0 + tx - SHARED_F; }
#pragma unroll
    for (int p = 0; p < 4; ++p) {
        int r = ty + p * 8;
        t[r][tx] = src[(size_t)(k0 + r) * ld + c];
    }
    __syncthreads();
    bf16* dst = Wcat + (size_t)e * HIDDEN * HID_F;
#pragma unroll
    for (int p = 0; p < 4; ++p) {
        int rn = ty + p * 8;
        dst[(size_t)(n0 + rn) * HID_F + k0 + tx] = (bf16)t[tx][rn];
    }
}

// LDS tile layout (R4, BK=64): row-major [128][64] bf16, 128 B/row = 8
// 16 B chunks; phys_chunk = c ^ (row&7). Staging permutes the GLOBAL source
// chunk per lane (dest of global_load_lds is fixed base+lane*16); frag
// reads XOR-correct with (lrow&7). Quarter-wave read phases span all 8
// chunk columns -> residual 2-way only (free, m136).
//
// XCD-gather swizzle (R3, kept): xcd = L&7, j = L>>3; mt = xcd*32 + j/NT,
// nt = j%NT -> each A-slab lives in exactly one XCD's L2.

// ---- GEMM 1: h = gelu(hb @ W1t^T + b1), bf16 out, BK=64 -----------------
__global__ __launch_bounds__(256) void fc1_gelu(
        const bf16* __restrict__ A,   // [32768][768]
        const bf16* __restrict__ Bt,  // [3072][768]
        const float* __restrict__ b1, // [3072]
        bf16* __restrict__ H) {       // [32768][3072]
    __shared__ alignas(16) bf16 As[128 * 64];
    __shared__ alignas(16) bf16 Bs[128 * 64];
    const int tid  = threadIdx.x;
    const int wave = tid >> 6, lane = tid & 63;
    const int wm = wave >> 1, wn = wave & 1;
    const int lrow = lane & 15, lk8 = lane >> 4;

    const int L   = blockIdx.x;        // 0..6143 ; NT=24
    const int xcd = L & 7;
    const int j   = L >> 3;
    const int jm  = j / 24;
    const int mt  = xcd * 32 + jm;
    const int nt  = j - jm * 24;
    const int m0 = mt * 128;
    const int n0 = nt * 128;

    // staging: one op = 8 rows x 128 B; lane -> row lane>>3, phys chunk lane&7
    const int srow8  = lane >> 3;                       // 0..7
    const int schunk = ((lane & 7) ^ srow8) * 8;        // logical src chunk, elems
    // frag read: logical chunk c = ks*4 + lk8 lives at phys c ^ (lrow&7)
    const int rc0 = ((lk8 ^ (lrow & 7))) * 8;           // ks=0 offset, elems
    // ks=1 offset = rc0 ^ 32 (chunk index ^4)

    const bf16* gA[4]; const bf16* gB[4];
    bf16* lA[4]; bf16* lB[4];
#pragma unroll
    for (int i = 0; i < 4; ++i) {
        int r0 = wave * 32 + i * 8;
        gA[i] = A  + (size_t)(m0 + r0 + srow8) * HIDDEN + schunk;
        gB[i] = Bt + (size_t)(n0 + r0 + srow8) * HIDDEN + schunk;
        lA[i] = As + r0 * 64 + lane * 8;
        lB[i] = Bs + r0 * 64 + lane * 8;
    }

    f32x4 acc[4][4] = {};
    for (int k0 = 0; k0 < HIDDEN; k0 += 64) {
#pragma unroll
        for (int i = 0; i < 4; ++i) {
            gl2lds16(gA[i], lA[i]); gl2lds16(gB[i], lB[i]);
            gA[i] += 64; gB[i] += 64;
        }
        __syncthreads();   // drains vmcnt -> LDS visible
#pragma unroll
        for (int ks = 0; ks < 2; ++ks) {
            const int ro = (ks ? (rc0 ^ 32) : rc0);
            bf16x8 af[4], bfr[4];
#pragma unroll
            for (int mi = 0; mi < 4; ++mi)
                af[mi] = *(const bf16x8*)(As + (wm * 64 + mi * 16 + lrow) * 64 + ro);
#pragma unroll
            for (int ni = 0; ni < 4; ++ni)
                bfr[ni] = *(const bf16x8*)(Bs + (wn * 64 + ni * 16 + lrow) * 64 + ro);
#pragma unroll
            for (int mi = 0; mi < 4; ++mi)
#pragma unroll
                for (int ni = 0; ni < 4; ++ni)
                    acc[mi][ni] = __builtin_amdgcn_mfma_f32_16x16x32_bf16(
                        af[mi], bfr[ni], acc[mi][ni], 0, 0, 0);
        }
        __syncthreads();   // protect LDS before next stage
    }
#pragma unroll
    for (int mi = 0; mi < 4; ++mi) {
#pragma unroll
        for (int ni = 0; ni < 4; ++ni) {
            int col = n0 + wn * 64 + ni * 16 + lrow;
            float bias = b1[col];
#pragma unroll
            for (int r = 0; r < 4; ++r) {
                int row = m0 + wm * 64 + mi * 16 + lk8 * 4 + r;
                float v = acc[mi][ni][r] + bias;
                H[(size_t)row * HID_F + col] = (bf16)gelu_fast(v);
            }
        }
    }
}

// ---- GEMM 2: out = h @ Wcat[idx[b]]^T + bias_cat, fp32 out, BK=64 -------
__global__ __launch_bounds__(256) void fc2_moe(
        const bf16* __restrict__ H,     // [32768][3072]
        const bf16* __restrict__ Wcat,  // [6][768][3072]
        const float* __restrict__ b2,   // [576]
        const float* __restrict__ be,   // [6][192]
        const int*  __restrict__ idx,   // [32]
        float* __restrict__ Out) {      // [32768][768]
    __shared__ alignas(16) bf16 As[128 * 64];
    __shared__ alignas(16) bf16 Bs[128 * 64];
    const int tid  = threadIdx.x;
    const int wave = tid >> 6, lane = tid & 63;
    const int wm = wave >> 1, wn = wave & 1;
    const int lrow = lane & 15, lk8 = lane >> 4;

    const int L   = blockIdx.x;        // 0..1535 ; NT=6
    const int xcd = L & 7;
    const int j   = L >> 3;
    const int jm  = j / 6;
    const int mt  = xcd * 32 + jm;
    const int nt  = j - jm * 6;
    const int m0 = mt * 128;
    const int n0 = nt * 128;

    int e = idx[mt >> 3];                       // 8 m-tiles per batch elem
    e = e < 0 ? 0 : (e > NEXP - 1 ? NEXP - 1 : e);
    const bf16* Btp = Wcat + (size_t)e * HIDDEN * HID_F;

    const int srow8  = lane >> 3;
    const int schunk = ((lane & 7) ^ srow8) * 8;
    const int rc0 = ((lk8 ^ (lrow & 7))) * 8;

    const bf16* gA[4]; const bf16* gB[4];
    bf16* lA[4]; bf16* lB[4];
#pragma unroll
    for (int i = 0; i < 4; ++i) {
        int r0 = wave * 32 + i * 8;
        gA[i] = H   + (size_t)(m0 + r0 + srow8) * HID_F + schunk;
        gB[i] = Btp + (size_t)(n0 + r0 + srow8) * HID_F + schunk;
        lA[i] = As + r0 * 64 + lane * 8;
        lB[i] = Bs + r0 * 64 + lane * 8;
    }

    f32x4 acc[4][4] = {};
    for (int k0 = 0; k0 < HID_F; k0 += 64) {
#pragma unroll
        for (int i = 0; i < 4; ++i) {
            gl2lds16(gA[i], lA[i]); gl2lds16(gB[i], lB[i]);
            gA[i] += 64; gB[i] += 64;
        }
        __syncthreads();
#pragma unroll
        for (int ks = 0; ks < 2; ++ks) {
            const int ro = (ks ? (rc0 ^ 32) : rc0);
            bf16x8 af[4], bfr[4];
#pragma unroll
            for (int mi = 0; mi < 4; ++mi)
                af[mi] = *(const bf16x8*)(As + (wm * 64 + mi * 16 + lrow) * 64 + ro);
#pragma unroll
            for (int ni = 0; ni < 4; ++ni)
                bfr[ni] = *(const bf16x8*)(Bs + (wn * 64 + ni * 16 + lrow) * 64 + ro);
#pragma unroll
            for (int mi = 0; mi < 4; ++mi)
#pragma unroll
                for (int ni = 0; ni < 4; ++ni)
                    acc[mi][ni] = __builtin_amdgcn_mfma_f32_16x16x32_bf16(
                        af[mi], bfr[ni], acc[mi][ni], 0, 0, 0);
        }
        __syncthreads();
    }
#pragma unroll
    for (int mi = 0; mi < 4; ++mi) {
#pragma unroll
        for (int ni = 0; ni < 4; ++ni) {
            int col = n0 + wn * 64 + ni * 16 + lrow;
            float bias = (col < SHARED_F) ? b2[col] : be[e * PART + col - SHARED_F];
#pragma unroll
            for (int r = 0; r < 4; ++r) {
                int row = m0 + wm * 64 + mi * 16 + lk8 * 4 + r;
                Out[(size_t)row * HIDDEN + col] = acc[mi][ni][r] + bias;
            }
        }
    }
}

extern "C" void kernel_launch(void* const* d_in, const int* in_sizes, int n_in,
                              void* d_out, int out_size, void* d_ws, size_t ws_size,
                              hipStream_t stream) {
    const float* hidden = (const float*)d_in[0];
    const int*   idx    = (const int*)d_in[1];
    const float* W1     = (const float*)d_in[2];
    const float* b1     = (const float*)d_in[3];
    const float* W2     = (const float*)d_in[4];
    const float* b2     = (const float*)d_in[5];
    const float* We     = (const float*)d_in[6];
    const float* be     = (const float*)d_in[7];
    float* out = (float*)d_out;

    // workspace layout (bytes)
    char* ws = (char*)d_ws;
    bf16* hb   = (bf16*)(ws);                       //  50,331,648 B: [32768][768]
    bf16* h    = (bf16*)(ws + 50331648);            // 201,326,592 B: [32768][3072]
    bf16* W1t  = (bf16*)(ws + 251658240);           //   4,718,592 B: [3072][768]
    bf16* Wcat = (bf16*)(ws + 256376832);           //  28,311,552 B: [6][768][3072]
    // total 284,688,384 B

    // prep
    cvt_f32_bf16<<<4096, 256, 0, stream>>>(
        (const float4*)hidden, (bf16x4*)hb, (M_TOK * HIDDEN) / 4);
    transpose_cvt<<<dim3(HID_F / 32, HIDDEN / 32), 256, 0, stream>>>(
        W1, W1t, HIDDEN, HID_F);
    build_wcat<<<dim3(HIDDEN / 32, HID_F / 32, NEXP), 256, 0, stream>>>(
        W2, We, Wcat);

    // GEMM 1: [32768,768] x [768,3072] -> h (bf16, gelu fused), XCD-swizzled
    fc1_gelu<<<(HID_F / 128) * (M_TOK / 128), 256, 0, stream>>>(hb, W1t, b1, h);

    // GEMM 2: [32768,3072] x [3072,768] -> out (fp32, bias fused), XCD-swizzled
    fc2_moe<<<(HIDDEN / 128) * (M_TOK / 128), 256, 0, stream>>>(
        h, Wcat, b2, be, idx, out);
}